// Round 1
// baseline (182.230 us; speedup 1.0000x reference)
//
#include <hip/hip_runtime.h>

// Problem constants
#define BATCH 32
#define CIN   256
#define CR    8
#define HDIM  56
#define WDIM  56
#define HW    3136          // 56*56, = 49 * 64 (waves never straddle batch rows)
#define COUT  44            // 8 z_norm + 36 interactions

// ---------------------------------------------------------------------------
// Kernel 1: 1x1 conv reduce (256 -> 8) + BatchNorm(inference) + ReLU.
// One thread per pixel. x is NCHW so for fixed (b,cin) consecutive pixels are
// contiguous -> fully coalesced 256B/wave loads. Weight reads are wave-uniform
// (loop-counter indexed) -> scalar loads. Output z written channels-last
// [pixel][8] so kernel 2 gets 32B-contiguous per-pixel channel vectors.
// ---------------------------------------------------------------------------
__global__ __launch_bounds__(64) void k1_reduce_bn_relu(
    const float* __restrict__ x, const float* __restrict__ wr,
    const float* __restrict__ gamma, const float* __restrict__ beta,
    const float* __restrict__ mean, const float* __restrict__ var,
    float* __restrict__ z)
{
    const int t = blockIdx.x * 64 + threadIdx.x;   // global pixel id
    const int b = t / HW;
    const int p = t - b * HW;
    const float* xp = x + (size_t)b * CIN * HW + p;

    float acc[CR];
#pragma unroll
    for (int c = 0; c < CR; ++c) acc[c] = 0.f;

#pragma unroll 16
    for (int cin = 0; cin < CIN; ++cin) {
        const float xv = xp[(size_t)cin * HW];
#pragma unroll
        for (int c = 0; c < CR; ++c)
            acc[c] = fmaf(xv, wr[c * CIN + cin], acc[c]);
    }

    // BatchNorm (inference) + ReLU
    float v[CR];
#pragma unroll
    for (int c = 0; c < CR; ++c) {
        const float inv = gamma[c] / sqrtf(var[c] + 1e-5f);
        const float sh  = beta[c] - mean[c] * inv;
        v[c] = fmaxf(fmaf(acc[c], inv, sh), 0.f);
    }

    float4* zp = reinterpret_cast<float4*>(z + (size_t)t * CR);
    zp[0] = make_float4(v[0], v[1], v[2], v[3]);
    zp[1] = make_float4(v[4], v[5], v[6], v[7]);
}

// ---------------------------------------------------------------------------
// Kernel 2: depthwise 3x3 (pad 1) * scale, per-pixel L2 norms over 8 channels,
// 36 upper-triangular pairwise products, write 44 output channels (NCHW).
// ---------------------------------------------------------------------------
__global__ __launch_bounds__(64) void k2_dw_norm_inter(
    const float* __restrict__ z, const float* __restrict__ wdw,
    const float* __restrict__ scale, float* __restrict__ out)
{
    const int t = blockIdx.x * 64 + threadIdx.x;   // global pixel id
    const int b = t / HW;
    const int p = t - b * HW;
    const int h = p / WDIM;
    const int w = p - h * WDIM;

    // center channels (channels-last, 32B contiguous)
    const float4 c0 = reinterpret_cast<const float4*>(z + (size_t)t * CR)[0];
    const float4 c1 = reinterpret_cast<const float4*>(z + (size_t)t * CR)[1];
    const float zc[CR] = {c0.x, c0.y, c0.z, c0.w, c1.x, c1.y, c1.z, c1.w};

    float tw[CR];
#pragma unroll
    for (int c = 0; c < CR; ++c) tw[c] = 0.f;

#pragma unroll
    for (int dy = -1; dy <= 1; ++dy) {
        const int hh = h + dy;
        const bool okh = (hh >= 0) && (hh < HDIM);
#pragma unroll
        for (int dx = -1; dx <= 1; ++dx) {
            const int ww = w + dx;
            const bool ok = okh && (ww >= 0) && (ww < WDIM);
            if (ok) {
                const float* zn = z + ((size_t)(b * HW + hh * WDIM + ww)) * CR;
                const float4 n0 = reinterpret_cast<const float4*>(zn)[0];
                const float4 n1 = reinterpret_cast<const float4*>(zn)[1];
                const float nv[CR] = {n0.x, n0.y, n0.z, n0.w, n1.x, n1.y, n1.z, n1.w};
                const int k = (dy + 1) * 3 + (dx + 1);
#pragma unroll
                for (int c = 0; c < CR; ++c)
                    tw[c] = fmaf(nv[c], wdw[c * 9 + k], tw[c]);
            }
        }
    }

    float s1 = 0.f, s2 = 0.f;
#pragma unroll
    for (int c = 0; c < CR; ++c) {
        tw[c] *= scale[c];
        s1 = fmaf(zc[c], zc[c], s1);
        s2 = fmaf(tw[c], tw[c], s2);
    }
    const float r1 = 1.0f / fmaxf(sqrtf(s1), 1e-6f);
    const float r2 = 1.0f / fmaxf(sqrtf(s2), 1e-6f);

    float a[CR], tb[CR];
#pragma unroll
    for (int c = 0; c < CR; ++c) { a[c] = zc[c] * r1; tb[c] = tw[c] * r2; }

    float* op = out + (size_t)b * COUT * HW + p;
#pragma unroll
    for (int c = 0; c < CR; ++c)
        op[(size_t)c * HW] = a[c];

    int idx = CR;
#pragma unroll
    for (int i = 0; i < CR; ++i) {
#pragma unroll
        for (int j = i; j < CR; ++j) {
            op[(size_t)idx * HW] = a[i] * tb[j];
            ++idx;
        }
    }
}

extern "C" void kernel_launch(void* const* d_in, const int* in_sizes, int n_in,
                              void* d_out, int out_size, void* d_ws, size_t ws_size,
                              hipStream_t stream) {
    const float* x     = (const float*)d_in[0];
    const float* wr    = (const float*)d_in[1];
    const float* gamma = (const float*)d_in[2];
    const float* beta  = (const float*)d_in[3];
    const float* mean  = (const float*)d_in[4];
    const float* var   = (const float*)d_in[5];
    const float* wdw   = (const float*)d_in[6];
    const float* scale = (const float*)d_in[7];
    float* out = (float*)d_out;
    float* z   = (float*)d_ws;   // BATCH*HW*CR floats = 3.21 MB, channels-last

    const int npix = BATCH * HW;          // 100352 = 1568 * 64
    k1_reduce_bn_relu<<<npix / 64, 64, 0, stream>>>(x, wr, gamma, beta, mean, var, z);
    k2_dw_norm_inter<<<npix / 64, 64, 0, stream>>>(z, wdw, scale, out);
}